// Round 1
// baseline (207.474 us; speedup 1.0000x reference)
//
#include <hip/hip_runtime.h>
#include <math.h>

// Router: scores = x @ emb^T  [32768 x 64], top-2 per token, softmax over the
// two selected, scatter into 64-wide output (others exactly 0).
//
// Layout: lane = expert (64 lanes = 64 experts). Block = 256 threads = 4 waves,
// handles 64 tokens (16 tokens per wave). fp32 accumulation throughout (top-2
// selection is tie-sensitive; bf16/MFMA error would flip near-degenerate gaps).

constexpr int HDIM = 1024;   // hidden
constexpr int NEXP = 64;     // experts
constexpr int TPB  = 64;     // tokens per block
constexpr int BK   = 64;     // k-chunk staged in LDS
constexpr int NTHREADS = 256;
constexpr int NCHUNK = HDIM / BK;   // 16

__global__ __launch_bounds__(NTHREADS, 2)
void router_kernel(const float* __restrict__ x,
                   const float* __restrict__ emb,
                   float* __restrict__ out)
{
    // LDS tiles (float4-typed => 16B alignment guaranteed)
    __shared__ float4 xs4[TPB][BK / 4];    // 16 KiB  x[token][k] quads
    __shared__ float4 es4[NEXP][BK / 4];   // 16 KiB  emb[e][k] quads, XOR-swizzled

    const int tid  = threadIdx.x;
    const int lane = tid & 63;        // expert id for compute phase
    const int wave = tid >> 6;        // 0..3
    const int tok0 = blockIdx.x * TPB;

    // staging mapping: each thread loads 4 float4 (4 rows x one 16B quad)
    const int kq = tid & 15;          // quad index within chunk (k = kq*4)
    const int r0 = tid >> 4;          // row 0..15; rows r0 + 16*j

    float acc[16];
#pragma unroll
    for (int i = 0; i < 16; ++i) acc[i] = 0.f;

    float4 xr[4], er[4], xr2[4], er2[4];

    // prefetch chunk 0
#pragma unroll
    for (int j = 0; j < 4; ++j) {
        const int r = r0 + 16 * j;
        xr[j] = *(const float4*)(x   + (size_t)(tok0 + r) * HDIM + kq * 4);
        er[j] = *(const float4*)(emb + (size_t)r          * HDIM + kq * 4);
    }

    const int t0  = wave * 16;        // this wave's token sub-tile
    const int esw = lane & 15;        // read-side swizzle key

    for (int c = 0; c < NCHUNK; ++c) {
        __syncthreads();              // previous chunk's reads done
        // write staged regs -> LDS (emb quads XOR-swizzled per row)
#pragma unroll
        for (int j = 0; j < 4; ++j) {
            const int r = r0 + 16 * j;
            xs4[r][kq] = xr[j];
            es4[r][kq ^ (r & 15)] = er[j];
        }
        // issue next chunk's global loads (latency hidden under compute)
        if (c + 1 < NCHUNK) {
            const int k0 = (c + 1) * BK;
#pragma unroll
            for (int j = 0; j < 4; ++j) {
                const int r = r0 + 16 * j;
                xr2[j] = *(const float4*)(x   + (size_t)(tok0 + r) * HDIM + k0 + kq * 4);
                er2[j] = *(const float4*)(emb + (size_t)r          * HDIM + k0 + kq * 4);
            }
        }
        __syncthreads();              // tile ready

        // compute: per quad q: 1 swizzled b128 (emb, lane-varying, conflict-free)
        // + 16 broadcast b128 (x, wave-uniform) + 64 FMA
#pragma unroll 4
        for (int q = 0; q < BK / 4; ++q) {
            const float4 b = es4[lane][q ^ esw];
#pragma unroll
            for (int tt = 0; tt < 16; ++tt) {
                const float4 a = xs4[t0 + tt][q];
                acc[tt] = fmaf(a.x, b.x, acc[tt]);
                acc[tt] = fmaf(a.y, b.y, acc[tt]);
                acc[tt] = fmaf(a.z, b.z, acc[tt]);
                acc[tt] = fmaf(a.w, b.w, acc[tt]);
            }
        }

#pragma unroll
        for (int j = 0; j < 4; ++j) { xr[j] = xr2[j]; er[j] = er2[j]; }
    }

    // ---- epilogue: per-token top-2 across lanes (lane = expert) ----
#pragma unroll
    for (int tt = 0; tt < 16; ++tt) {
        // 1st max, lowest-index tie-break (matches jax.lax.top_k)
        float v = acc[tt];
        int   ei = lane;
#pragma unroll
        for (int off = 32; off >= 1; off >>= 1) {
            const float vo = __shfl_xor(v, off, 64);
            const int   eo = __shfl_xor(ei, off, 64);
            if (vo > v || (vo == v && eo < ei)) { v = vo; ei = eo; }
        }
        const float m1 = v;
        const int   e1 = ei;

        // 2nd max excluding e1
        float w = (lane == e1) ? -INFINITY : acc[tt];
        int   ej = lane;
#pragma unroll
        for (int off = 32; off >= 1; off >>= 1) {
            const float vo = __shfl_xor(w, off, 64);
            const int   eo = __shfl_xor(ej, off, 64);
            if (vo > w || (vo == w && eo < ej)) { w = vo; ej = eo; }
        }
        const float m2 = w;
        const int   e2 = ej;

        // softmax over {m1, m2} with max-subtraction, others exp(-inf)=0
        const float t  = expf(m2 - m1);
        const float dn = 1.f + t;
        const float p1 = 1.f / dn;
        const float p2 = t / dn;

        const float o = (lane == e1) ? p1 : (lane == e2) ? p2 : 0.f;
        out[(size_t)(tok0 + t0 + tt) * NEXP + lane] = o;
    }
}

extern "C" void kernel_launch(void* const* d_in, const int* in_sizes, int n_in,
                              void* d_out, int out_size, void* d_ws, size_t ws_size,
                              hipStream_t stream)
{
    const float* x   = (const float*)d_in[0];
    const float* emb = (const float*)d_in[1];
    float* out = (float*)d_out;

    const int n_tokens = in_sizes[0] / HDIM;     // 32768
    const int nblocks  = n_tokens / TPB;         // 512

    router_kernel<<<nblocks, NTHREADS, 0, stream>>>(x, emb, out);
}

// Round 2
// 163.094 us; speedup vs baseline: 1.2721x; 1.2721x over previous
//
#include <hip/hip_runtime.h>
#include <math.h>

// Router: scores = x @ emb^T [32768 x 64] fp32, top-2 per token, 2-way softmax
// scattered into 64-wide output.
//
// lane = expert (64 lanes = 64 experts). Block = 256 threads = 4 waves = 64
// tokens (wave owns 16 tokens, acc[16] per lane). K staged in BK=64 chunks.
// Staging uses global_load_lds DMA (no staging VGPRs -> no spill, which cost
// round-1 520 MB of scratch HBM writes). emb LDS tile is XOR-swizzled via
// pre-swizzled GLOBAL source (LDS dest must stay linear for global_load_lds).

constexpr int HDIM = 1024;
constexpr int NEXP = 64;
constexpr int TPB  = 64;            // tokens per block
constexpr int BK   = 64;            // k per chunk
constexpr int NQ   = BK / 4;        // 16 quads per row-chunk
constexpr int NTHREADS = 256;
constexpr int NCHUNK = HDIM / BK;   // 16

__global__ __launch_bounds__(NTHREADS, 2)
void router_kernel(const float* __restrict__ x,
                   const float* __restrict__ emb,
                   float* __restrict__ out)
{
    __shared__ float4 xs[2][TPB][NQ];    // 2 x 16 KiB, x[token][quad]
    __shared__ float4 es[2][NEXP][NQ];   // 2 x 16 KiB, emb[e][quad^(e&15)]

    const int tid  = threadIdx.x;
    const int lane = tid & 63;
    const int wave = tid >> 6;          // 0..3
    const int tok0 = blockIdx.x * TPB;

    const int lhi = lane >> 4;          // 0..3
    const int lq  = lane & 15;          // quad slot within a row

    // Issue DMA for chunk C into buffer P. Wave w stages rows 16w..16w+15
    // (4 gload_lds x 4 rows); LDS dest is linear in lane; emb source quad is
    // pre-swizzled so the READ-side XOR lands on emb[row][q].
#define STAGE(P, C)                                                            \
    do {                                                                       \
        _Pragma("unroll")                                                      \
        for (int j = 0; j < 4; ++j) {                                          \
            const int row = 16 * wave + 4 * j + lhi;                           \
            const float* gx = x + (size_t)(tok0 + row) * HDIM + (C) * BK       \
                                + lq * 4;                                      \
            const float* ge = emb + (size_t)row * HDIM + (C) * BK              \
                                + ((lq ^ (row & 15)) * 4);                     \
            __builtin_amdgcn_global_load_lds(                                  \
                (const __attribute__((address_space(1))) void*)gx,             \
                (__attribute__((address_space(3))) void*)&xs[P][row][lq],      \
                16, 0, 0);                                                     \
            __builtin_amdgcn_global_load_lds(                                  \
                (const __attribute__((address_space(1))) void*)ge,             \
                (__attribute__((address_space(3))) void*)&es[P][row][lq],      \
                16, 0, 0);                                                     \
        }                                                                      \
    } while (0)

    float acc[16];
#pragma unroll
    for (int i = 0; i < 16; ++i) acc[i] = 0.f;

    STAGE(0, 0);

    const int sw = lane & 15;           // read-side swizzle key
    int p = 0;

    for (int c = 0; c < NCHUNK; ++c) {
        __syncthreads();                // drains DMA for chunk c (vmcnt 0)
        if (c + 1 < NCHUNK) STAGE(p ^ 1, c + 1);   // lands before next barrier

        // lane's emb chunk row -> 16 float4 regs (lane-varying, swizzled)
        float4 eb[NQ];
#pragma unroll
        for (int q = 0; q < NQ; ++q) eb[q] = es[p][lane][q ^ sw];

        // 16 tokens x 64 k: broadcast x quad + 4 FMA each
#pragma unroll
        for (int tt = 0; tt < 16; ++tt) {
#pragma unroll
            for (int q = 0; q < NQ; ++q) {
                const float4 a = xs[p][wave * 16 + tt][q];
                acc[tt] = fmaf(a.x, eb[q].x, acc[tt]);
                acc[tt] = fmaf(a.y, eb[q].y, acc[tt]);
                acc[tt] = fmaf(a.z, eb[q].z, acc[tt]);
                acc[tt] = fmaf(a.w, eb[q].w, acc[tt]);
            }
        }
        p ^= 1;
    }

    // ---- epilogue: per-token top-2 across lanes (lane = expert) ----
    const int t0 = wave * 16;
#pragma unroll
    for (int tt = 0; tt < 16; ++tt) {
        // 1st max, lowest-index tie-break (matches jax.lax.top_k)
        float v = acc[tt];
        int   ei = lane;
#pragma unroll
        for (int off = 32; off >= 1; off >>= 1) {
            const float vo = __shfl_xor(v, off, 64);
            const int   eo = __shfl_xor(ei, off, 64);
            if (vo > v || (vo == v && eo < ei)) { v = vo; ei = eo; }
        }
        const float m1 = v;
        const int   e1 = ei;

        // 2nd max excluding e1
        float w = (lane == e1) ? -INFINITY : acc[tt];
        int   ej = lane;
#pragma unroll
        for (int off = 32; off >= 1; off >>= 1) {
            const float vo = __shfl_xor(w, off, 64);
            const int   eo = __shfl_xor(ej, off, 64);
            if (vo > w || (vo == w && eo < ej)) { w = vo; ej = eo; }
        }
        const float m2 = w;
        const int   e2 = ej;

        const float t  = expf(m2 - m1);
        const float dn = 1.f + t;
        const float p1 = 1.f / dn;
        const float p2 = t / dn;

        const float o = (lane == e1) ? p1 : (lane == e2) ? p2 : 0.f;
        out[(size_t)(tok0 + t0 + tt) * NEXP + lane] = o;
    }
#undef STAGE
}

extern "C" void kernel_launch(void* const* d_in, const int* in_sizes, int n_in,
                              void* d_out, int out_size, void* d_ws, size_t ws_size,
                              hipStream_t stream)
{
    const float* x   = (const float*)d_in[0];
    const float* emb = (const float*)d_in[1];
    float* out = (float*)d_out;

    const int n_tokens = in_sizes[0] / HDIM;     // 32768
    const int nblocks  = n_tokens / TPB;         // 512

    router_kernel<<<nblocks, NTHREADS, 0, stream>>>(x, emb, out);
}